// Round 8
// baseline (179.417 us; speedup 1.0000x reference)
//
#include <hip/hip_runtime.h>
#include <hip/hip_fp16.h>

typedef _Float16 half8 __attribute__((ext_vector_type(8)));
typedef _Float16 half4 __attribute__((ext_vector_type(4)));
typedef float floatx4 __attribute__((ext_vector_type(4)));

#define T_SEQ 2048
#define NB    8

// ---------------------------------------------------------------------------
// Kernel 0: prep — WqT f16 [64][768]
// ---------------------------------------------------------------------------
__global__ __launch_bounds__(256) void prep_kernel(
    const float* __restrict__ Wq, _Float16* __restrict__ WqT)
{
  const int h = blockIdx.x, tid = threadIdx.x;
  for (int k = tid; k < 768; k += 256)
    WqT[h * 768 + k] = (_Float16)Wq[k * 64 + h];
}

// ---------------------------------------------------------------------------
// Kernel 1: q = x @ Wq. Wave-autonomous: 1024 blocks x 64 threads, one wave
// per 16-row tile. A (x, HBM) and B (WqT, L2) both register double-buffered
// in groups of K=128. ISSUE ORDER per group: B first, then A — vmcnt is
// in-order, so the MFMA's wait on group g leaves group g+1 fully in flight.
// Zero LDS, zero barriers. Emits Ct = (|q|^2/8)*log2e + bias0*log2e + 8.
// ---------------------------------------------------------------------------
__global__ __launch_bounds__(64) void qproj_kernel(
    const float* __restrict__ x, const _Float16* __restrict__ WqT,
    const float* __restrict__ rel,
    _Float16* __restrict__ q16, _Float16* __restrict__ q16T,
    float* __restrict__ Ct)
{
  const int lane = threadIdx.x;
  const int n = lane & 15, quad = lane >> 4;
  const int r0 = blockIdx.x * 16;

  const float*    xp = x   + (size_t)(r0 + n) * 768 + quad * 8;
  const _Float16* wp = WqT + (size_t)n * 768 + quad * 8;

  float4 A[2][8];        // 2 groups x (4 chunks x 2 float4)
  half8  Bv[2][16];      // 2 groups x (4 chunks x 4 h-subtiles)

  #define LOAD_GROUP(buf, g)                                               \
    {                                                                      \
      _Pragma("unroll")                                                    \
      for (int c = 0; c < 4; ++c) {                                        \
        const int kc = 128 * (g) + 32 * c;                                 \
        Bv[buf][4 * c + 0] = *(const half8*)(wp + kc);                     \
        Bv[buf][4 * c + 1] = *(const half8*)(wp + 16 * 768 + kc);          \
        Bv[buf][4 * c + 2] = *(const half8*)(wp + 32 * 768 + kc);          \
        Bv[buf][4 * c + 3] = *(const half8*)(wp + 48 * 768 + kc);          \
      }                                                                    \
      _Pragma("unroll")                                                    \
      for (int c = 0; c < 4; ++c) {                                        \
        A[buf][2 * c]     = *(const float4*)(xp + 128 * (g) + 32 * c);     \
        A[buf][2 * c + 1] = *(const float4*)(xp + 128 * (g) + 32 * c + 4); \
      }                                                                    \
    }

  LOAD_GROUP(0, 0)
  LOAD_GROUP(1, 1)

  floatx4 acc[4];
  #pragma unroll
  for (int s = 0; s < 4; ++s) acc[s] = (floatx4){0.f, 0.f, 0.f, 0.f};

  #pragma unroll
  for (int g = 0; g < 6; ++g) {
    const int cur = g & 1;
    #pragma unroll
    for (int c = 0; c < 4; ++c) {
      half8 a;
      a[0] = (_Float16)A[cur][2 * c].x; a[1] = (_Float16)A[cur][2 * c].y;
      a[2] = (_Float16)A[cur][2 * c].z; a[3] = (_Float16)A[cur][2 * c].w;
      a[4] = (_Float16)A[cur][2 * c + 1].x; a[5] = (_Float16)A[cur][2 * c + 1].y;
      a[6] = (_Float16)A[cur][2 * c + 1].z; a[7] = (_Float16)A[cur][2 * c + 1].w;
      acc[0] = __builtin_amdgcn_mfma_f32_16x16x32_f16(a, Bv[cur][4 * c + 0], acc[0], 0, 0, 0);
      acc[1] = __builtin_amdgcn_mfma_f32_16x16x32_f16(a, Bv[cur][4 * c + 1], acc[1], 0, 0, 0);
      acc[2] = __builtin_amdgcn_mfma_f32_16x16x32_f16(a, Bv[cur][4 * c + 2], acc[2], 0, 0, 0);
      acc[3] = __builtin_amdgcn_mfma_f32_16x16x32_f16(a, Bv[cur][4 * c + 3], acc[3], 0, 0, 0);
    }
    if (g + 2 < 6) LOAD_GROUP(cur, g + 2)   // refill consumed buffer
  }
  #undef LOAD_GROUP

  // epilogue (registers only). C layout: row = quad*4+r (t), col = sub*16+n (h)
  const float b0v = rel[2047] * 1.44269504f;
  float ss[4] = {0.f, 0.f, 0.f, 0.f};
  const int bb = r0 >> 11, tt = (r0 & 2047) + quad * 4;
  #pragma unroll
  for (int sub = 0; sub < 4; ++sub) {
    half4 hv;
    #pragma unroll
    for (int r = 0; r < 4; ++r) {
      float v = acc[sub][r];
      q16[(size_t)(r0 + quad * 4 + r) * 64 + sub * 16 + n] = (_Float16)v;
      hv[r] = (_Float16)v;
      ss[r] += v * v;
    }
    *(half4*)(q16T + (size_t)(bb * 64 + sub * 16 + n) * T_SEQ + tt) = hv;
  }
  #pragma unroll
  for (int off = 1; off < 16; off <<= 1) {
    #pragma unroll
    for (int r = 0; r < 4; ++r) ss[r] += __shfl_xor(ss[r], off);
  }
  if (n == 0) {
    #pragma unroll
    for (int r = 0; r < 4; ++r)
      Ct[r0 + quad * 4 + r] = ss[r] * 0.18033688f + b0v + 8.0f;
  }
}

// ---------------------------------------------------------------------------
// Kernel 2: attention, fixed-offset softmax. 1024 blocks x 256 thr (4 waves);
// block = one 16-row Q-tile, qi = (u<64) ? u : 191-u  -> with round-robin
// dispatch each CU's 4 blocks sum to exactly 258 k-tiles (balanced). All
// 1024 blocks co-resident (34.4 KB LDS -> 4 blocks/CU, 16 waves/CU).
// k-split 4 across waves, register KV double-buffer, 4-slot LDS combine.
// ---------------------------------------------------------------------------
__global__ __launch_bounds__(256, 4) void attn_kernel(
    const _Float16* __restrict__ q16, const _Float16* __restrict__ q16T,
    const float* __restrict__ rel, const float* __restrict__ Ct,
    float* __restrict__ out)
{
  __shared__ __align__(16) _Float16 Pbuf[4 * 16 * 72];  // 9216 B
  __shared__ float Obuf[4 * 16 * 65];                   // 16640 B
  __shared__ float Lbuf[4 * 16];                        // 256 B
  __shared__ float biasL[2080];                         // 8320 B

  const int bi = blockIdx.x;
  const int b  = bi & 7;
  const int u  = bi >> 3;               // [0,128)
  const int qi = (u < 64) ? u : 191 - u;
  const int t0 = qi * 16;
  const int kfull = t0 >> 6;            // tiles [0,kfull) unmasked; kfull = diag

  const int tid  = threadIdx.x;
  const int w    = tid >> 6;
  const int lane = tid & 63;
  const int n    = lane & 15, quad = lane >> 4;

  // stage bias slice (*log2e)
  {
    const int lo = 2032 - t0, cnt = t0 + 31;
    for (int i = tid; i < cnt; i += 256) biasL[i] = rel[lo + i] * 1.44269504f;
  }

  half8 aq0, aq1;
  {
    const _Float16* qrow = q16 + (size_t)(b * T_SEQ + t0 + n) * 64 + quad * 8;
    aq0 = *(const half8*)qrow;
    aq1 = *(const half8*)(qrow + 32);
  }
  float ctv[4];
  #pragma unroll
  for (int r = 0; r < 4; ++r)
    ctv[r] = Ct[b * T_SEQ + t0 + 4 * quad + r];

  floatx4 O[4];
  #pragma unroll
  for (int s = 0; s < 4; ++s) O[s] = (floatx4){0.f, 0.f, 0.f, 0.f};
  floatx4 den = (floatx4){0.f, 0.f, 0.f, 0.f};
  const half8 ones = {(_Float16)1, (_Float16)1, (_Float16)1, (_Float16)1,
                      (_Float16)1, (_Float16)1, (_Float16)1, (_Float16)1};

  _Float16* Pw = Pbuf + w * 1152;
  const float ksc = 0.125f * 1.44269504f;
  const _Float16* vbase = q16T + (size_t)(b * 64 + n) * T_SEQ + quad * 8;

  __syncthreads();                      // biasL visible

  #define LOAD_KV(S0, K, V)                                                   \
    {                                                                         \
      _Pragma("unroll")                                                       \
      for (int sub = 0; sub < 4; ++sub) {                                     \
        const _Float16* kp =                                                  \
            q16 + (size_t)(b * T_SEQ + (S0) + sub * 16 + n) * 64 + quad * 8;  \
        K[2 * sub]     = *(const half8*)kp;                                   \
        K[2 * sub + 1] = *(const half8*)(kp + 32);                            \
      }                                                                       \
      _Pragma("unroll")                                                       \
      for (int sh = 0; sh < 4; ++sh) {                                        \
        V[sh]     = *(const half8*)(vbase + (size_t)(sh * 16) * T_SEQ + (S0));\
        V[4 + sh] = *(const half8*)(vbase + (size_t)(sh * 16) * T_SEQ + (S0) + 32); \
      }                                                                       \
    }

  half8 cK[8], cV[8], nK[8], nV[8];
  int kt = w;
  if (kt <= kfull) LOAD_KV(kt * 64, cK, cV);

  for (; kt <= kfull; kt += 4) {
    const int ktn = kt + 4;
    if (ktn <= kfull) LOAD_KV(ktn * 64, nK, nV);

    const int  s0 = kt * 64;
    const bool dg = (kt == kfull);
    const int  j  = (t0 - s0) >> 4;     // valid when dg

    #pragma unroll
    for (int sub = 0; sub < 4; ++sub) {
      if (dg && sub > j) {
        #pragma unroll
        for (int r = 0; r < 4; ++r)
          Pw[(4 * quad + r) * 72 + sub * 16 + n] = (_Float16)0.f;
        continue;
      }
      floatx4 sc = (floatx4){0.f, 0.f, 0.f, 0.f};
      sc = __builtin_amdgcn_mfma_f32_16x16x32_f16(aq0, cK[2 * sub], sc, 0, 0, 0);
      sc = __builtin_amdgcn_mfma_f32_16x16x32_f16(aq1, cK[2 * sub + 1], sc, 0, 0, 0);
      const int smin = s0 + sub * 16;
      #pragma unroll
      for (int r = 0; r < 4; ++r) {
        float bv = biasL[15 + smin + n - 4 * quad - r];
        float pv = exp2f(fmaf(sc[r], ksc, bv) - ctv[r]);
        if (dg && sub == j && n > 4 * quad + r) pv = 0.f;    // causal diagonal
        Pw[(4 * quad + r) * 72 + sub * 16 + n] = (_Float16)pv;
      }
    }

    #pragma unroll
    for (int ch = 0; ch < 2; ++ch) {
      half8 pf = *(const half8*)(Pw + n * 72 + ch * 32 + quad * 8);
      den = __builtin_amdgcn_mfma_f32_16x16x32_f16(pf, ones, den, 0, 0, 0);
      #pragma unroll
      for (int sh = 0; sh < 4; ++sh)
        O[sh] = __builtin_amdgcn_mfma_f32_16x16x32_f16(pf, cV[ch * 4 + sh],
                                                       O[sh], 0, 0, 0);
    }

    #pragma unroll
    for (int i = 0; i < 8; ++i) { cK[i] = nK[i]; cV[i] = nV[i]; }
  }
  #undef LOAD_KV

  // per-wave partials
  #pragma unroll
  for (int sub = 0; sub < 4; ++sub)
    #pragma unroll
    for (int r = 0; r < 4; ++r)
      Obuf[w * 1040 + (4 * quad + r) * 65 + sub * 16 + n] = O[sub][r];
  if (n == 0) {
    #pragma unroll
    for (int r = 0; r < 4; ++r)
      Lbuf[w * 16 + 4 * quad + r] = den[r];
  }
  __syncthreads();

  // 4-way combine + output
  #pragma unroll
  for (int k = 0; k < 4; ++k) {
    const int e = tid + k * 256;
    const int row = e >> 6, h = e & 63;
    float num = Obuf[row * 65 + h]        + Obuf[1040 + row * 65 + h] +
                Obuf[2080 + row * 65 + h] + Obuf[3120 + row * 65 + h];
    float d   = Lbuf[row] + Lbuf[16 + row] + Lbuf[32 + row] + Lbuf[48 + row];
    out[(size_t)(b * T_SEQ + t0 + row) * 64 + h] = num / d;
  }
}

// ---------------------------------------------------------------------------
extern "C" void kernel_launch(void* const* d_in, const int* in_sizes, int n_in,
                              void* d_out, int out_size, void* d_ws, size_t ws_size,
                              hipStream_t stream) {
  const float* x   = (const float*)d_in[0];
  const float* Wq  = (const float*)d_in[1];
  const float* rel = (const float*)d_in[2];
  float* out = (float*)d_out;

  _Float16* q16  = (_Float16*)d_ws;                    // [8][2048][64]
  _Float16* q16T = q16  + (size_t)NB * T_SEQ * 64;     // [8][64][2048]
  _Float16* WqT  = q16T + (size_t)NB * T_SEQ * 64;     // [64][768]
  float*    Ct   = (float*)(WqT + 64 * 768);           // [16384]

  prep_kernel <<<64,   256, 0, stream>>>(Wq, WqT);
  qproj_kernel<<<1024,  64, 0, stream>>>(x, WqT, rel, q16, q16T, Ct);
  attn_kernel <<<1024, 256, 0, stream>>>(q16, q16T, rel, Ct, out);
}

// Round 9
// 129.059 us; speedup vs baseline: 1.3902x; 1.3902x over previous
//
#include <hip/hip_runtime.h>
#include <hip/hip_fp16.h>

typedef _Float16 half8 __attribute__((ext_vector_type(8)));
typedef _Float16 half4 __attribute__((ext_vector_type(4)));
typedef float floatx4 __attribute__((ext_vector_type(4)));

#define T_SEQ 2048
#define NB    8

// ---------------------------------------------------------------------------
// Kernel 0: prep — WqTs: Wq pre-swizzled into MFMA B-fragment order.
// Block b = cg*4 + t (cg = 32-col k-chunk, t = 16-wide h-subtile); lane l
// holds B[n = l&15 (h), k = 8*(l>>4)+j]. GEMM then loads B as contiguous
// 1 KB per instruction.
// ---------------------------------------------------------------------------
__global__ __launch_bounds__(64) void prep_kernel(
    const float* __restrict__ Wq, _Float16* __restrict__ WqTs)
{
  const int b = blockIdx.x;            // [0,96): cg*4 + t
  const int cg = b >> 2, t = b & 3;
  const int l = threadIdx.x, n = l & 15, q = l >> 4;
  const int h = 16 * t + n;
  half8 v;
  #pragma unroll
  for (int j = 0; j < 8; ++j)
    v[j] = (_Float16)Wq[(32 * cg + 8 * q + j) * 64 + h];
  *(half8*)(WqTs + (size_t)b * 512 + l * 8) = v;
}

// ---------------------------------------------------------------------------
// Kernel 1: q = x @ Wq. 1024 blocks x 256 thr. Phase 1: perfectly coalesced
// float4 loads of the 16x768 tile, cast f16, store to 24.7 KB LDS (row pad
// 770 -> ~4-way max frag-read aliasing). Phase 2: k-split 4 waves, MFMA with
// contiguous B loads (WqTs) and zero cvt in the loop. Phase 3: LDS combine
// (aliases the x tile), Ct, q16, q16T. 4+ blocks/CU, 16+ waves/CU: each
// block's stage overlaps other blocks' compute; ~190 KB in flight per CU.
// ---------------------------------------------------------------------------
__global__ __launch_bounds__(256, 4) void qproj_kernel(
    const float* __restrict__ x, const _Float16* __restrict__ WqTs,
    const float* __restrict__ rel,
    _Float16* __restrict__ q16, _Float16* __restrict__ q16T,
    float* __restrict__ Ct)
{
  __shared__ __align__(16) char smem[24704];
  _Float16* xs   = (_Float16*)smem;                  // [16][770] f16
  float*    cbuf = (float*)smem;                     // alias: 4 x [16][65] f32
  _Float16* qs   = (_Float16*)(smem + 16640);        // alias: [16][66] f16
  float*    sq   = (float*)(smem + 16640 + 2112);    // alias: [16] f32

  const int tid  = threadIdx.x;
  const int w    = tid >> 6, lane = tid & 63;
  const int n    = lane & 15, quad = lane >> 4;
  const int r0   = blockIdx.x * 16;

  // ---- phase 1: coalesced load + cast + LDS store ----
  #pragma unroll
  for (int i = 0; i < 12; ++i) {
    const int e   = tid + 256 * i;        // [0,3072) float4 index
    const int row = e / 192, c4 = e - row * 192;
    float4 v = *(const float4*)(x + (size_t)(r0 + row) * 768 + 4 * c4);
    half4 hv;
    hv[0] = (_Float16)v.x; hv[1] = (_Float16)v.y;
    hv[2] = (_Float16)v.z; hv[3] = (_Float16)v.w;
    *(half4*)(xs + row * 770 + 4 * c4) = hv;
  }
  __syncthreads();

  // ---- phase 2: MFMA, k-split 192 per wave ----
  floatx4 acc[4];
  #pragma unroll
  for (int s = 0; s < 4; ++s) acc[s] = (floatx4){0.f, 0.f, 0.f, 0.f};

  const int k0 = w * 192;
  #pragma unroll
  for (int c = 0; c < 6; ++c) {
    const int cg = w * 6 + c;
    const _Float16* bp = WqTs + (size_t)cg * 2048 + lane * 8;
    half8 b0 = *(const half8*)(bp);
    half8 b1 = *(const half8*)(bp + 512);
    half8 b2 = *(const half8*)(bp + 1024);
    half8 b3 = *(const half8*)(bp + 1536);
    half8 a  = *(const half8*)(xs + n * 770 + k0 + 32 * c + 8 * quad);
    acc[0] = __builtin_amdgcn_mfma_f32_16x16x32_f16(a, b0, acc[0], 0, 0, 0);
    acc[1] = __builtin_amdgcn_mfma_f32_16x16x32_f16(a, b1, acc[1], 0, 0, 0);
    acc[2] = __builtin_amdgcn_mfma_f32_16x16x32_f16(a, b2, acc[2], 0, 0, 0);
    acc[3] = __builtin_amdgcn_mfma_f32_16x16x32_f16(a, b3, acc[3], 0, 0, 0);
  }
  __syncthreads();                        // xs dead -> cbuf/qs/sq alias safe

  // ---- phase 3: 4-slot combine ----
  #pragma unroll
  for (int sub = 0; sub < 4; ++sub)
    #pragma unroll
    for (int r = 0; r < 4; ++r)
      cbuf[w * 1040 + (4 * quad + r) * 65 + sub * 16 + n] = acc[sub][r];
  __syncthreads();

  const float b0v = rel[2047] * 1.44269504f;
  #pragma unroll
  for (int k = 0; k < 4; ++k) {
    const int e = tid + 256 * k;
    const int row = e >> 6, h = e & 63;   // row wave-uniform
    float s = cbuf[row * 65 + h]        + cbuf[1040 + row * 65 + h] +
              cbuf[2080 + row * 65 + h] + cbuf[3120 + row * 65 + h];
    q16[(size_t)(r0 + row) * 64 + h] = (_Float16)s;
    qs[row * 66 + h] = (_Float16)s;
    float ss = s * s;
    #pragma unroll
    for (int off = 1; off < 64; off <<= 1) ss += __shfl_xor(ss, off);
    if (lane == 0) sq[row] = ss;
  }
  __syncthreads();

  if (tid < 16)
    Ct[r0 + tid] = sq[tid] * 0.18033688f + b0v + 8.0f;

  {
    const int h = tid >> 2, rq = (tid & 3) * 4;
    half4 hv;
    hv[0] = qs[(rq + 0) * 66 + h]; hv[1] = qs[(rq + 1) * 66 + h];
    hv[2] = qs[(rq + 2) * 66 + h]; hv[3] = qs[(rq + 3) * 66 + h];
    const int bb = r0 >> 11, tt = r0 & 2047;
    *(half4*)(q16T + (size_t)(bb * 64 + h) * T_SEQ + tt + rq) = hv;
  }
}

// ---------------------------------------------------------------------------
// Kernel 2: attention, fixed-offset softmax. 1024 blocks x 256 thr (4 waves);
// block = one 16-row Q-tile, qi = (u<64) ? u : 191-u  -> each CU's 4 resident
// blocks sum to a constant 66 k-tile iterations (balanced under round-robin).
// k-split 4 across waves, register KV double-buffer, 4-slot LDS combine.
// __launch_bounds__(256,2): r6-proven (VGPR 116, no spill, 4 blocks/CU).
// ---------------------------------------------------------------------------
__global__ __launch_bounds__(256, 2) void attn_kernel(
    const _Float16* __restrict__ q16, const _Float16* __restrict__ q16T,
    const float* __restrict__ rel, const float* __restrict__ Ct,
    float* __restrict__ out)
{
  __shared__ __align__(16) _Float16 Pbuf[4 * 16 * 72];  // 9216 B
  __shared__ float Obuf[4 * 16 * 65];                   // 16640 B
  __shared__ float Lbuf[4 * 16];                        // 256 B
  __shared__ float biasL[2080];                         // 8320 B

  const int bi = blockIdx.x;
  const int b  = bi & 7;
  const int u  = bi >> 3;               // [0,128)
  const int qi = (u < 64) ? u : 191 - u;
  const int t0 = qi * 16;
  const int kfull = t0 >> 6;            // tiles [0,kfull) unmasked; kfull = diag

  const int tid  = threadIdx.x;
  const int w    = tid >> 6;
  const int lane = tid & 63;
  const int n    = lane & 15, quad = lane >> 4;

  // stage bias slice (*log2e)
  {
    const int lo = 2032 - t0, cnt = t0 + 31;
    for (int i = tid; i < cnt; i += 256) biasL[i] = rel[lo + i] * 1.44269504f;
  }

  half8 aq0, aq1;
  {
    const _Float16* qrow = q16 + (size_t)(b * T_SEQ + t0 + n) * 64 + quad * 8;
    aq0 = *(const half8*)qrow;
    aq1 = *(const half8*)(qrow + 32);
  }
  float ctv[4];
  #pragma unroll
  for (int r = 0; r < 4; ++r)
    ctv[r] = Ct[b * T_SEQ + t0 + 4 * quad + r];

  floatx4 O[4];
  #pragma unroll
  for (int s = 0; s < 4; ++s) O[s] = (floatx4){0.f, 0.f, 0.f, 0.f};
  floatx4 den = (floatx4){0.f, 0.f, 0.f, 0.f};
  const half8 ones = {(_Float16)1, (_Float16)1, (_Float16)1, (_Float16)1,
                      (_Float16)1, (_Float16)1, (_Float16)1, (_Float16)1};

  _Float16* Pw = Pbuf + w * 1152;
  const float ksc = 0.125f * 1.44269504f;
  const _Float16* vbase = q16T + (size_t)(b * 64 + n) * T_SEQ + quad * 8;

  __syncthreads();                      // biasL visible

  #define LOAD_KV(S0, K, V)                                                   \
    {                                                                         \
      _Pragma("unroll")                                                       \
      for (int sub = 0; sub < 4; ++sub) {                                     \
        const _Float16* kp =                                                  \
            q16 + (size_t)(b * T_SEQ + (S0) + sub * 16 + n) * 64 + quad * 8;  \
        K[2 * sub]     = *(const half8*)kp;                                   \
        K[2 * sub + 1] = *(const half8*)(kp + 32);                            \
      }                                                                       \
      _Pragma("unroll")                                                       \
      for (int sh = 0; sh < 4; ++sh) {                                        \
        V[sh]     = *(const half8*)(vbase + (size_t)(sh * 16) * T_SEQ + (S0));\
        V[4 + sh] = *(const half8*)(vbase + (size_t)(sh * 16) * T_SEQ + (S0) + 32); \
      }                                                                       \
    }

  half8 cK[8], cV[8], nK[8], nV[8];
  int kt = w;
  if (kt <= kfull) LOAD_KV(kt * 64, cK, cV);

  for (; kt <= kfull; kt += 4) {
    const int ktn = kt + 4;
    if (ktn <= kfull) LOAD_KV(ktn * 64, nK, nV);

    const int  s0 = kt * 64;
    const bool dg = (kt == kfull);
    const int  j  = (t0 - s0) >> 4;     // valid when dg

    #pragma unroll
    for (int sub = 0; sub < 4; ++sub) {
      if (dg && sub > j) {
        #pragma unroll
        for (int r = 0; r < 4; ++r)
          Pw[(4 * quad + r) * 72 + sub * 16 + n] = (_Float16)0.f;
        continue;
      }
      floatx4 sc = (floatx4){0.f, 0.f, 0.f, 0.f};
      sc = __builtin_amdgcn_mfma_f32_16x16x32_f16(aq0, cK[2 * sub], sc, 0, 0, 0);
      sc = __builtin_amdgcn_mfma_f32_16x16x32_f16(aq1, cK[2 * sub + 1], sc, 0, 0, 0);
      const int smin = s0 + sub * 16;
      #pragma unroll
      for (int r = 0; r < 4; ++r) {
        float bv = biasL[15 + smin + n - 4 * quad - r];
        float pv = exp2f(fmaf(sc[r], ksc, bv) - ctv[r]);
        if (dg && sub == j && n > 4 * quad + r) pv = 0.f;    // causal diagonal
        Pw[(4 * quad + r) * 72 + sub * 16 + n] = (_Float16)pv;
      }
    }

    #pragma unroll
    for (int ch = 0; ch < 2; ++ch) {
      half8 pf = *(const half8*)(Pw + n * 72 + ch * 32 + quad * 8);
      den = __builtin_amdgcn_mfma_f32_16x16x32_f16(pf, ones, den, 0, 0, 0);
      #pragma unroll
      for (int sh = 0; sh < 4; ++sh)
        O[sh] = __builtin_amdgcn_mfma_f32_16x16x32_f16(pf, cV[ch * 4 + sh],
                                                       O[sh], 0, 0, 0);
    }

    #pragma unroll
    for (int i = 0; i < 8; ++i) { cK[i] = nK[i]; cV[i] = nV[i]; }
  }
  #undef LOAD_KV

  // per-wave partials
  #pragma unroll
  for (int sub = 0; sub < 4; ++sub)
    #pragma unroll
    for (int r = 0; r < 4; ++r)
      Obuf[w * 1040 + (4 * quad + r) * 65 + sub * 16 + n] = O[sub][r];
  if (n == 0) {
    #pragma unroll
    for (int r = 0; r < 4; ++r)
      Lbuf[w * 16 + 4 * quad + r] = den[r];
  }
  __syncthreads();

  // 4-way combine + output
  #pragma unroll
  for (int k = 0; k < 4; ++k) {
    const int e = tid + k * 256;
    const int row = e >> 6, h = e & 63;
    float num = Obuf[row * 65 + h]        + Obuf[1040 + row * 65 + h] +
                Obuf[2080 + row * 65 + h] + Obuf[3120 + row * 65 + h];
    float d   = Lbuf[row] + Lbuf[16 + row] + Lbuf[32 + row] + Lbuf[48 + row];
    out[(size_t)(b * T_SEQ + t0 + row) * 64 + h] = num / d;
  }
}

// ---------------------------------------------------------------------------
extern "C" void kernel_launch(void* const* d_in, const int* in_sizes, int n_in,
                              void* d_out, int out_size, void* d_ws, size_t ws_size,
                              hipStream_t stream) {
  const float* x   = (const float*)d_in[0];
  const float* Wq  = (const float*)d_in[1];
  const float* rel = (const float*)d_in[2];
  float* out = (float*)d_out;

  _Float16* q16   = (_Float16*)d_ws;                    // [8][2048][64]
  _Float16* q16T  = q16  + (size_t)NB * T_SEQ * 64;     // [8][64][2048]
  _Float16* WqTs  = q16T + (size_t)NB * T_SEQ * 64;     // [96][512] swizzled
  float*    Ct    = (float*)(WqTs + 96 * 512);          // [16384]

  prep_kernel <<<96,    64, 0, stream>>>(Wq, WqTs);
  qproj_kernel<<<1024, 256, 0, stream>>>(x, WqTs, rel, q16, q16T, Ct);
  attn_kernel <<<1024, 256, 0, stream>>>(q16, q16T, rel, Ct, out);
}

// Round 10
// 111.734 us; speedup vs baseline: 1.6058x; 1.1551x over previous
//
#include <hip/hip_runtime.h>
#include <hip/hip_fp16.h>

typedef _Float16 half8 __attribute__((ext_vector_type(8)));
typedef _Float16 half4 __attribute__((ext_vector_type(4)));
typedef float floatx4 __attribute__((ext_vector_type(4)));

#define T_SEQ 2048
#define NB    8

// ---------------------------------------------------------------------------
// Kernel 0: prep — WqTs: Wq pre-swizzled into MFMA B-fragment order.
// ---------------------------------------------------------------------------
__global__ __launch_bounds__(64) void prep_kernel(
    const float* __restrict__ Wq, _Float16* __restrict__ WqTs)
{
  const int b = blockIdx.x;            // [0,96): cg*4 + t
  const int cg = b >> 2, t = b & 3;
  const int l = threadIdx.x, n = l & 15, q = l >> 4;
  const int h = 16 * t + n;
  half8 v;
  #pragma unroll
  for (int j = 0; j < 8; ++j)
    v[j] = (_Float16)Wq[(32 * cg + 8 * q + j) * 64 + h];
  *(half8*)(WqTs + (size_t)b * 512 + l * 8) = v;
}

// ---------------------------------------------------------------------------
// Kernel 1: q = x @ Wq. 1024 blocks x 256 thr; 16 rows/block. Phase 1:
// coalesced f4 loads -> f16 LDS tile. Phase 2: k-split-4 MFMA (swizzled B).
// Phase 3: emit Q/K fragments (q16F) and V fragments (v16F) in MFMA operand
// order — attention then does ZERO gathers — plus Ct.
// ---------------------------------------------------------------------------
__global__ __launch_bounds__(256, 4) void qproj_kernel(
    const float* __restrict__ x, const _Float16* __restrict__ WqTs,
    const float* __restrict__ rel,
    _Float16* __restrict__ q16F, _Float16* __restrict__ v16F,
    float* __restrict__ Ct)
{
  __shared__ __align__(16) char smem[24704];
  _Float16* xs   = (_Float16*)smem;                  // [16][770] f16
  float*    cbuf = (float*)smem;                     // alias: 4 x [16][65] f32
  _Float16* qs   = (_Float16*)(smem + 16640);        // alias: [16][72] f16
  float*    sq   = (float*)(smem + 16640 + 2304);    // alias: [16] f32

  const int tid  = threadIdx.x;
  const int w    = tid >> 6, lane = tid & 63;
  const int n    = lane & 15, quad = lane >> 4;
  const int r0   = blockIdx.x * 16;

  // ---- phase 1: coalesced load + cast + LDS store ----
  #pragma unroll
  for (int i = 0; i < 12; ++i) {
    const int e   = tid + 256 * i;        // [0,3072) float4 index
    const int row = e / 192, c4 = e - row * 192;
    float4 v = *(const float4*)(x + (size_t)(r0 + row) * 768 + 4 * c4);
    half4 hv;
    hv[0] = (_Float16)v.x; hv[1] = (_Float16)v.y;
    hv[2] = (_Float16)v.z; hv[3] = (_Float16)v.w;
    *(half4*)(xs + row * 770 + 4 * c4) = hv;
  }
  __syncthreads();

  // ---- phase 2: MFMA, k-split 192 per wave ----
  floatx4 acc[4];
  #pragma unroll
  for (int s = 0; s < 4; ++s) acc[s] = (floatx4){0.f, 0.f, 0.f, 0.f};

  const int k0 = w * 192;
  #pragma unroll
  for (int c = 0; c < 6; ++c) {
    const int cg = w * 6 + c;
    const _Float16* bp = WqTs + (size_t)cg * 2048 + lane * 8;
    half8 b0 = *(const half8*)(bp);
    half8 b1 = *(const half8*)(bp + 512);
    half8 b2 = *(const half8*)(bp + 1024);
    half8 b3 = *(const half8*)(bp + 1536);
    half8 a  = *(const half8*)(xs + n * 770 + k0 + 32 * c + 8 * quad);
    acc[0] = __builtin_amdgcn_mfma_f32_16x16x32_f16(a, b0, acc[0], 0, 0, 0);
    acc[1] = __builtin_amdgcn_mfma_f32_16x16x32_f16(a, b1, acc[1], 0, 0, 0);
    acc[2] = __builtin_amdgcn_mfma_f32_16x16x32_f16(a, b2, acc[2], 0, 0, 0);
    acc[3] = __builtin_amdgcn_mfma_f32_16x16x32_f16(a, b3, acc[3], 0, 0, 0);
  }
  __syncthreads();                        // xs dead -> cbuf/qs/sq alias safe

  // ---- phase 3a: 4-slot combine -> qs (f16) + sumsq ----
  #pragma unroll
  for (int sub = 0; sub < 4; ++sub)
    #pragma unroll
    for (int r = 0; r < 4; ++r)
      cbuf[w * 1040 + (4 * quad + r) * 65 + sub * 16 + n] = acc[sub][r];
  __syncthreads();

  const float b0v = rel[2047] * 1.44269504f;
  #pragma unroll
  for (int k = 0; k < 4; ++k) {
    const int e = tid + 256 * k;
    const int row = e >> 6, h = e & 63;   // row wave-uniform
    float s = cbuf[row * 65 + h]        + cbuf[1040 + row * 65 + h] +
              cbuf[2080 + row * 65 + h] + cbuf[3120 + row * 65 + h];
    qs[row * 72 + h] = (_Float16)s;
    float ss = s * s;
    #pragma unroll
    for (int off = 1; off < 64; off <<= 1) ss += __shfl_xor(ss, off);
    if (lane == 0) sq[row] = ss;
  }
  __syncthreads();

  if (tid < 16)
    Ct[r0 + tid] = sq[tid] * 0.18033688f + b0v + 8.0f;

  // ---- phase 3b: fragment emission ----
  if (tid < 128) {
    // Q/K fragments: lane l holds rows (l&15), k = ch*32 + (l>>4)*8 + j
    const int ch = tid >> 6, l = tid & 63;
    half8 f = *(const half8*)(qs + (l & 15) * 72 + ch * 32 + (l >> 4) * 8);
    *(half8*)(q16F + ((size_t)(r0 >> 4) * 2 + ch) * 512 + l * 8) = f;
  } else {
    // V fragments: output (h, p): 8 consecutive s-rows (8p..8p+8) at column h
    const int u = tid - 128, h = u >> 1, p = u & 1;
    const int mg = r0 >> 4;               // global 16-row block index
    const int b  = mg >> 7, ml = mg & 127;
    const int kt = ml >> 2, chv = (ml >> 1) & 1, q = 2 * (ml & 1) + p;
    half8 f;
    #pragma unroll
    for (int j = 0; j < 8; ++j)
      f[j] = qs[(8 * p + j) * 72 + h];
    const size_t off =
        ((((size_t)(b * 32 + kt) * 2 + chv) * 4 + (h >> 4)) * 64 +
         ((h & 15) + 16 * q)) * 8;
    *(half8*)(v16F + off) = f;
  }
}

// ---------------------------------------------------------------------------
// Kernel 2: attention, fixed-offset softmax. 1024 blocks x 256 thr (4 waves);
// block = one 16-row Q-tile, qi = (u<64) ? u : 191-u (balanced). k-split 4,
// register KV double-buffer, 4-slot LDS combine. ALL Q/K/V loads are now
// single-segment contiguous 1 KB wave-loads from the fragment tensors.
// ---------------------------------------------------------------------------
__global__ __launch_bounds__(256, 2) void attn_kernel(
    const _Float16* __restrict__ q16F, const _Float16* __restrict__ v16F,
    const float* __restrict__ rel, const float* __restrict__ Ct,
    float* __restrict__ out)
{
  __shared__ __align__(16) _Float16 Pbuf[4 * 16 * 72];  // 9216 B
  __shared__ float Obuf[4 * 16 * 65];                   // 16640 B
  __shared__ float Lbuf[4 * 16];                        // 256 B
  __shared__ float biasL[2080];                         // 8320 B

  const int bi = blockIdx.x;
  const int b  = bi & 7;
  const int u  = bi >> 3;               // [0,128)
  const int qi = (u < 64) ? u : 191 - u;
  const int t0 = qi * 16;
  const int kfull = t0 >> 6;            // tiles [0,kfull) unmasked; kfull = diag

  const int tid  = threadIdx.x;
  const int w    = tid >> 6;
  const int lane = tid & 63;
  const int n    = lane & 15, quad = lane >> 4;

  // stage bias slice (*log2e)
  {
    const int lo = 2032 - t0, cnt = t0 + 31;
    for (int i = tid; i < cnt; i += 256) biasL[i] = rel[lo + i] * 1.44269504f;
  }

  const _Float16* kfbase = q16F + (size_t)(b * 128) * 1024 + lane * 8;
  const _Float16* vfbase = v16F + (size_t)(b * 32) * 4096 + lane * 8;

  half8 aq0, aq1;
  {
    const _Float16* qf = q16F + ((size_t)(b * 128 + (t0 >> 4))) * 1024 + lane * 8;
    aq0 = *(const half8*)qf;
    aq1 = *(const half8*)(qf + 512);
  }
  float ctv[4];
  #pragma unroll
  for (int r = 0; r < 4; ++r)
    ctv[r] = Ct[b * T_SEQ + t0 + 4 * quad + r];

  floatx4 O[4];
  #pragma unroll
  for (int s = 0; s < 4; ++s) O[s] = (floatx4){0.f, 0.f, 0.f, 0.f};
  floatx4 den = (floatx4){0.f, 0.f, 0.f, 0.f};
  const half8 ones = {(_Float16)1, (_Float16)1, (_Float16)1, (_Float16)1,
                      (_Float16)1, (_Float16)1, (_Float16)1, (_Float16)1};

  _Float16* Pw = Pbuf + w * 1152;
  const float ksc = 0.125f * 1.44269504f;

  __syncthreads();                      // biasL visible

  #define LOAD_KV(KT, K, V)                                                   \
    {                                                                         \
      const _Float16* kp = kfbase + (size_t)(KT) * 4096;                      \
      _Pragma("unroll")                                                       \
      for (int sub = 0; sub < 4; ++sub) {                                     \
        K[2 * sub]     = *(const half8*)(kp + sub * 1024);                    \
        K[2 * sub + 1] = *(const half8*)(kp + sub * 1024 + 512);              \
      }                                                                       \
      const _Float16* vp = vfbase + (size_t)(KT) * 4096;                      \
      _Pragma("unroll")                                                       \
      for (int sh = 0; sh < 4; ++sh) {                                        \
        V[sh]     = *(const half8*)(vp + sh * 512);                           \
        V[4 + sh] = *(const half8*)(vp + 2048 + sh * 512);                    \
      }                                                                       \
    }

  half8 cK[8], cV[8], nK[8], nV[8];
  int kt = w;
  if (kt <= kfull) LOAD_KV(kt, cK, cV);

  for (; kt <= kfull; kt += 4) {
    const int ktn = kt + 4;
    if (ktn <= kfull) LOAD_KV(ktn, nK, nV);

    const int  s0 = kt * 64;
    const bool dg = (kt == kfull);
    const int  j  = (t0 - s0) >> 4;     // valid when dg

    #pragma unroll
    for (int sub = 0; sub < 4; ++sub) {
      if (dg && sub > j) {
        #pragma unroll
        for (int r = 0; r < 4; ++r)
          Pw[(4 * quad + r) * 72 + sub * 16 + n] = (_Float16)0.f;
        continue;
      }
      floatx4 sc = (floatx4){0.f, 0.f, 0.f, 0.f};
      sc = __builtin_amdgcn_mfma_f32_16x16x32_f16(aq0, cK[2 * sub], sc, 0, 0, 0);
      sc = __builtin_amdgcn_mfma_f32_16x16x32_f16(aq1, cK[2 * sub + 1], sc, 0, 0, 0);
      const int smin = s0 + sub * 16;
      #pragma unroll
      for (int r = 0; r < 4; ++r) {
        float bv = biasL[15 + smin + n - 4 * quad - r];
        float pv = exp2f(fmaf(sc[r], ksc, bv) - ctv[r]);
        if (dg && sub == j && n > 4 * quad + r) pv = 0.f;    // causal diagonal
        Pw[(4 * quad + r) * 72 + sub * 16 + n] = (_Float16)pv;
      }
    }

    #pragma unroll
    for (int ch = 0; ch < 2; ++ch) {
      half8 pf = *(const half8*)(Pw + n * 72 + ch * 32 + quad * 8);
      den = __builtin_amdgcn_mfma_f32_16x16x32_f16(pf, ones, den, 0, 0, 0);
      #pragma unroll
      for (int sh = 0; sh < 4; ++sh)
        O[sh] = __builtin_amdgcn_mfma_f32_16x16x32_f16(pf, cV[ch * 4 + sh],
                                                       O[sh], 0, 0, 0);
    }

    #pragma unroll
    for (int i = 0; i < 8; ++i) { cK[i] = nK[i]; cV[i] = nV[i]; }
  }
  #undef LOAD_KV

  // per-wave partials
  #pragma unroll
  for (int sub = 0; sub < 4; ++sub)
    #pragma unroll
    for (int r = 0; r < 4; ++r)
      Obuf[w * 1040 + (4 * quad + r) * 65 + sub * 16 + n] = O[sub][r];
  if (n == 0) {
    #pragma unroll
    for (int r = 0; r < 4; ++r)
      Lbuf[w * 16 + 4 * quad + r] = den[r];
  }
  __syncthreads();

  // 4-way combine + output
  #pragma unroll
  for (int k = 0; k < 4; ++k) {
    const int e = tid + k * 256;
    const int row = e >> 6, h = e & 63;
    float num = Obuf[row * 65 + h]        + Obuf[1040 + row * 65 + h] +
                Obuf[2080 + row * 65 + h] + Obuf[3120 + row * 65 + h];
    float d   = Lbuf[row] + Lbuf[16 + row] + Lbuf[32 + row] + Lbuf[48 + row];
    out[(size_t)(b * T_SEQ + t0 + row) * 64 + h] = num / d;
  }
}

// ---------------------------------------------------------------------------
extern "C" void kernel_launch(void* const* d_in, const int* in_sizes, int n_in,
                              void* d_out, int out_size, void* d_ws, size_t ws_size,
                              hipStream_t stream) {
  const float* x   = (const float*)d_in[0];
  const float* Wq  = (const float*)d_in[1];
  const float* rel = (const float*)d_in[2];
  float* out = (float*)d_out;

  _Float16* q16F = (_Float16*)d_ws;                    // [8*128][2][512]  2 MB
  _Float16* v16F = q16F + (size_t)NB * 128 * 1024;     // [8*32][2][4][512] 2 MB
  _Float16* WqTs = v16F + (size_t)NB * 32 * 4096;      // [96][512] swizzled
  float*    Ct   = (float*)(WqTs + 96 * 512);          // [16384]

  prep_kernel <<<96,    64, 0, stream>>>(Wq, WqTs);
  qproj_kernel<<<1024, 256, 0, stream>>>(x, WqTs, rel, q16F, v16F, Ct);
  attn_kernel <<<1024, 256, 0, stream>>>(q16F, v16F, rel, Ct, out);
}